// Round 12
// baseline (1568.294 us; speedup 1.0000x reference)
//
#include <hip/hip_runtime.h>
#include <stdint.h>

#define T_STEPS 800
#define NBATCH  32
#define SST     1024
#define ROW     5120   // floats per (t, n) row
#define RING    5      // LDS ring depth (800 % 5 == 0)

#define SCAN_BLOCKS 64
#define COPY_BLOCKS 192
#define GRID (SCAN_BLOCKS + COPY_BLOCKS)

// 16B-block swizzle (involution, verified loader-write == compute-read):
// spreads the consume's stride-5-block pattern across all 8 bank groups.
__device__ __forceinline__ int swz(int p) { return p ^ ((p >> 3) & 7); }

__device__ __forceinline__ float lse5(float v0, float v1, float v2, float v3, float v4) {
  float m = fmaxf(fmaxf(fmaxf(v0, v1), fmaxf(v2, v3)), v4);
  float s = __expf(v0 - m) + __expf(v1 - m) + __expf(v2 - m) +
            __expf(v3 - m) + __expf(v4 - m);
  return m + __logf(s);
}

#define WAITVM(N) do { \
  asm volatile("s_waitcnt vmcnt(" #N ")" ::: "memory"); \
  __builtin_amdgcn_sched_barrier(0); } while (0)

// Block barrier draining LDS ops only; global traffic stays in flight.
__device__ __forceinline__ void barrier_lgkm() {
  asm volatile("s_waitcnt lgkmcnt(0)" ::: "memory");
  __builtin_amdgcn_s_barrier();
  asm volatile("" ::: "memory");
}

// ---------------- loader waves ----------------
// Loader l owns row-quarter floats [1280l, 1280l+1280): 5 float4/lane/row.
// Register pipeline of RING rows; plain loads (compiler inserts exact waits;
// our WAITVM + sched fences control placement). ds_write lands the row in
// the ring with the 16B-block swizzle.
template <int DIR>
__device__ void loader_run(const float* __restrict__ base, int l, int lane,
                           float (*ring)[ROW]) {
  float4 vb[RING][5];
  // Per-op global float4 index within a row: 320l + 64k + lane.
  int gofs[5], lofs[5];
#pragma unroll
  for (int k = 0; k < 5; ++k) {
    const int p = 320 * l + 64 * k + lane;
    gofs[k] = 4 * p;            // float offset in source row
    lofs[k] = swz(p) << 2;      // float offset in LDS slot (swizzled)
  }

#define L_ISSUE(slot, r) do { \
    const int t_ = DIR ? (T_STEPS - 1 - (r)) : (r); \
    const float* rp_ = base + (size_t)t_ * (NBATCH * ROW); \
    _Pragma("unroll") \
    for (int k = 0; k < 5; ++k) vb[slot][k] = *(const float4*)(rp_ + gofs[k]); \
  } while (0)

#define L_WRITE(slot) do { \
    _Pragma("unroll") \
    for (int k = 0; k < 5; ++k) \
      *(float4*)(&ring[slot][0] + lofs[k]) = vb[slot][k]; \
  } while (0)

  // Prologue: issue rows 0..4; cert row 0; write row 0 -> slot 0.
  __builtin_amdgcn_sched_barrier(0);
  L_ISSUE(0, 0); L_ISSUE(1, 1); L_ISSUE(2, 2); L_ISSUE(3, 3); L_ISSUE(4, 4);
  __builtin_amdgcn_sched_barrier(0);
  WAITVM(20);
  L_WRITE(0);
  barrier_lgkm();

  // Steps 0..799. At step s: issue row s+5 into slot s%5, cert+write row s+1
  // (slot (s+1)%5). Static 5-phase unroll keeps all indices constant.
  for (int p5 = 0; p5 < T_STEPS; p5 += RING) {
#pragma unroll
    for (int i = 0; i < RING; ++i) {
      const int s = p5 + i;
      const int slot_w = (i + 1) % RING;   // row s+1
      if (s + RING < T_STEPS) {
        __builtin_amdgcn_sched_barrier(0);
        L_ISSUE(i, s + RING);
        __builtin_amdgcn_sched_barrier(0);
        WAITVM(20);
        L_WRITE(slot_w);
      } else {
        // tail: no issue; cert row s+1 among remaining in-flight rows
        const int rem = T_STEPS - 1 - s;   // rows s+1..799 outstanding
        if (rem == 4) WAITVM(15);
        else if (rem == 3) WAITVM(10);
        else if (rem == 2) WAITVM(5);
        else if (rem == 1) WAITVM(0);
        if (s + 1 < T_STEPS) L_WRITE(slot_w);
      }
      barrier_lgkm();
    }
  }
#undef L_ISSUE
#undef L_WRITE
}

// ---------------- compute waves ----------------
// DIR=0 (fwd): thread u owns states {4u..4u+3}; gathers abuf[u>>2 + 256k].
// DIR=1 (bwd): thread u owns states {u+256j}; gathers abuf[4u..4u+3].
template <int DIR>
__device__ void compute_run(float* __restrict__ out, int n, int u,
                            float (*ring)[ROW], float (*abuf)[SST]) {
  float* outn = out + (size_t)n * (T_STEPS + 1) * SST;
  float a[4] = {0.f, 0.f, 0.f, 0.f};

  int fvo[5];
#pragma unroll
  for (int m = 0; m < 5; ++m) fvo[m] = swz(5 * u + m) << 2;
  int svo[4];
#pragma unroll
  for (int j = 0; j < 4; ++j)
    svo[j] = (swz((5 * u) / 4 + 320 * j) << 2) | ((5 * u) & 3);

  // init alpha[0]/beta[T] = 0
  {
    const float4 z = {0.f, 0.f, 0.f, 0.f};
    *(float4*)&abuf[0][4 * u] = z;
    const size_t t0 = DIR ? (size_t)T_STEPS : 0;
    ((float4*)(outn + t0 * SST))[u] = z;
  }
  barrier_lgkm();

  int cs = 0;
  for (int s = 0; s < T_STEPS; ++s) {
    const float* rb = ring[cs];
    const int cur = s & 1, nxt = cur ^ 1;

    const float4 q0 = *(const float4*)(rb + fvo[0]);
    const float4 q1 = *(const float4*)(rb + fvo[1]);
    const float4 q2 = *(const float4*)(rb + fvo[2]);
    const float4 q3 = *(const float4*)(rb + fvo[3]);
    const float4 q4 = *(const float4*)(rb + fvo[4]);
    float fv[20];
    fv[0]=q0.x; fv[1]=q0.y; fv[2]=q0.z; fv[3]=q0.w;
    fv[4]=q1.x; fv[5]=q1.y; fv[6]=q1.z; fv[7]=q1.w;
    fv[8]=q2.x; fv[9]=q2.y; fv[10]=q2.z; fv[11]=q2.w;
    fv[12]=q3.x; fv[13]=q3.y; fv[14]=q3.z; fv[15]=q3.w;
    fv[16]=q4.x; fv[17]=q4.y; fv[18]=q4.z; fv[19]=q4.w;

    float na[4];
    if constexpr (!DIR) {
      const int q = u >> 2;
      const float p0 = abuf[cur][q];
      const float p1 = abuf[cur][q + 256];
      const float p2 = abuf[cur][q + 512];
      const float p3 = abuf[cur][q + 768];
#pragma unroll
      for (int j = 0; j < 4; ++j) {
        na[j] = lse5(fv[5*j] + a[j], fv[5*j+1] + p0, fv[5*j+2] + p1,
                     fv[5*j+3] + p2, fv[5*j+4] + p3);
        a[j] = na[j];
      }
      const float4 o = {na[0], na[1], na[2], na[3]};
      ((float4*)(outn + (size_t)(s + 1) * SST))[u] = o;
      *(float4*)&abuf[nxt][4 * u] = o;
    } else {
      const float4 pv = *(const float4*)&abuf[cur][4 * u];
      const int t = T_STEPS - 1 - s;
#pragma unroll
      for (int j = 0; j < 4; ++j) {
        na[j] = lse5(rb[svo[j]] + a[j], fv[1+j] + pv.x, fv[6+j] + pv.y,
                     fv[11+j] + pv.z, fv[16+j] + pv.w);
        a[j] = na[j];
        outn[(size_t)t * SST + u + 256 * j] = na[j];
        abuf[nxt][u + 256 * j] = na[j];
      }
    }
    barrier_lgkm();
    cs = (cs + 1 == RING) ? 0 : cs + 1;
  }
}

__global__ __launch_bounds__(512, 1) void mega(const float* __restrict__ scores,
                                               float* __restrict__ out0,
                                               float* __restrict__ bwdo,
                                               float* __restrict__ fposts) {
  __shared__ float ring[RING][ROW];   // 100 KB (swizzled 16B blocks)
  __shared__ float abuf[2][SST];      // 8 KB
  const int b = blockIdx.x;
  const int tid = threadIdx.x;

  if (b < SCAN_BLOCKS) {
    const int n = (b < NBATCH) ? b : (b - NBATCH);
    const float* base = scores + (size_t)n * ROW;
    if (b < NBATCH) {
      if (tid < 256) compute_run<0>(fposts, n, tid, ring, abuf);
      else           loader_run<0>(base, (tid >> 6) - 4, tid & 63, ring);
    } else {
      if (tid < 256) compute_run<1>(bwdo, n, tid, ring, abuf);
      else           loader_run<1>(base, (tid >> 6) - 4, tid & 63, ring);
    }
  } else {
    // copy army: out0[n][t][:] = scores[t][n][:]
    const int cb = b - SCAN_BLOCKS;
    for (int r = cb; r < NBATCH * T_STEPS; r += COPY_BLOCKS) {
      const int t = r / NBATCH, n2 = r % NBATCH;
      const float4* src = (const float4*)(scores + (size_t)r * ROW);
      float4* dst = (float4*)(out0 + ((size_t)n2 * T_STEPS + t) * ROW);
      for (int i = tid; i < ROW / 4; i += 512) dst[i] = src[i];
    }
  }
}

// One wave per row of 1024: posts = softmax(fwd + bwd), in place over fwd buffer.
__global__ __launch_bounds__(256) void posts_kernel(float* __restrict__ fp,
                                                    const float* __restrict__ bp) {
  const int lane = threadIdx.x & 63;
  const int wid  = threadIdx.x >> 6;
  const size_t row = (size_t)blockIdx.x * 4 + wid;
  float* f = fp + row * SST;
  const float* b = bp + row * SST;

  float x[16];
#pragma unroll
  for (int k = 0; k < 4; ++k) {
    const float4 fv = ((const float4*)f)[lane + 64 * k];
    const float4 bv = ((const float4*)b)[lane + 64 * k];
    x[4 * k + 0] = fv.x + bv.x;
    x[4 * k + 1] = fv.y + bv.y;
    x[4 * k + 2] = fv.z + bv.z;
    x[4 * k + 3] = fv.w + bv.w;
  }
  float m = x[0];
#pragma unroll
  for (int j = 1; j < 16; ++j) m = fmaxf(m, x[j]);
#pragma unroll
  for (int off = 32; off >= 1; off >>= 1) m = fmaxf(m, __shfl_xor(m, off));
  float ssum = 0.0f;
#pragma unroll
  for (int j = 0; j < 16; ++j) { x[j] = __expf(x[j] - m); ssum += x[j]; }
#pragma unroll
  for (int off = 32; off >= 1; off >>= 1) ssum += __shfl_xor(ssum, off);
  const float inv = 1.0f / ssum;
#pragma unroll
  for (int k = 0; k < 4; ++k) {
    float4 o;
    o.x = x[4 * k + 0] * inv;
    o.y = x[4 * k + 1] * inv;
    o.z = x[4 * k + 2] * inv;
    o.w = x[4 * k + 3] * inv;
    ((float4*)f)[lane + 64 * k] = o;
  }
}

extern "C" void kernel_launch(void* const* d_in, const int* in_sizes, int n_in,
                              void* d_out, int out_size, void* d_ws, size_t ws_size,
                              hipStream_t stream) {
  (void)in_sizes; (void)n_in; (void)d_ws; (void)ws_size; (void)out_size;
  const float* scores = (const float*)d_in[0];
  float* out = (float*)d_out;
  float* out0   = out;                                                  // (32,800,5120)
  float* bwdo   = out + (size_t)NBATCH * T_STEPS * ROW;                 // (32,801,1024)
  float* fposts = bwdo + (size_t)NBATCH * (T_STEPS + 1) * SST;          // (32,801,1024)

  mega<<<GRID, 512, 0, stream>>>(scores, out0, bwdo, fposts);
  posts_kernel<<<(NBATCH * (T_STEPS + 1)) / 4, 256, 0, stream>>>(fposts, bwdo);
}

// Round 13
// 737.273 us; speedup vs baseline: 2.1272x; 2.1272x over previous
//
#include <hip/hip_runtime.h>

#define T_STEPS 800
#define NBATCH  32
#define SST     1024
#define ROW     5120            // floats per (t, n) row
#define STRIDE  (NBATCH * ROW)  // floats between consecutive t rows
#define NSLOT   4               // LDS ring slots

__device__ __forceinline__ float lse5(float v0, float v1, float v2, float v3, float v4) {
  float m = fmaxf(fmaxf(fmaxf(v0, v1), fmaxf(v2, v3)), v4);
  float s = __expf(v0 - m) + __expf(v1 - m) + __expf(v2 - m) +
            __expf(v3 - m) + __expf(v4 - m);
  return m + __logf(s);
}

#define WAITVM(N) do { \
  asm volatile("s_waitcnt vmcnt(" #N ")" ::: "memory"); \
  __builtin_amdgcn_sched_barrier(0); } while (0)

// Block barrier draining LDS ops only; global traffic stays in flight.
__device__ __forceinline__ void barrier_lgkm() {
  asm volatile("s_waitcnt lgkmcnt(0)" ::: "memory");
  __builtin_amdgcn_s_barrier();
  asm volatile("" ::: "memory");
}

// ---------------- loader waves (waves 4..7) ----------------
// Loader l owns floats [1280l, 1280l+1280) of each row; lane handles 16B at
// 4*lane + 256k, k=0..4. Pipeline: 3 row-sets of 5 NAMED float4 regs
// (A,B,C = rows r with r%3 = 0,1,2). At step s: issue row s+3, cert row s+2
// (fwd WAITVM(10): 5 newer loads + 5 newer out0 stores; bwd WAITVM(5)),
// ds_write row s+2 to slot (s+2)%NSLOT, fwd: store row s+2 to out0.
template <int DIR>
__device__ void loader_run(const float* __restrict__ base,
                           float* __restrict__ out0n, int l, int lane,
                           float* __restrict__ ring) {
  const int loff = 1280 * l + 4 * lane;
  const ptrdiff_t str = DIR ? -(ptrdiff_t)STRIDE : (ptrdiff_t)STRIDE;
  const float* gIss = base + (size_t)(DIR ? (T_STEPS - 1) * STRIDE : 0) + loff;
  float* ringl = ring + loff;

  float4 A0, A1, A2, A3, A4, B0, B1, B2, B3, B4, C0, C1, C2, C3, C4;

#define LOADSET(R0,R1,R2,R3,R4) do { \
    const float4* gp_ = (const float4*)gIss; \
    R0 = gp_[0]; R1 = gp_[64]; R2 = gp_[128]; R3 = gp_[192]; R4 = gp_[256]; \
    gIss += str; } while (0)

#define WRITESET(R0,R1,R2,R3,R4) do { \
    float4* lw_ = (float4*)lsWr; \
    lw_[0] = R0; lw_[64] = R1; lw_[128] = R2; lw_[192] = R3; lw_[256] = R4; \
    if constexpr (!DIR) { \
      float4* op_ = (float4*)oSt; \
      op_[0] = R0; op_[64] = R1; op_[128] = R2; op_[192] = R3; op_[256] = R4; \
      oSt += ROW; } \
    wslot = (wslot + 1) & (NSLOT - 1); \
    lsWr = ringl + wslot * ROW; } while (0)

  // Prologue: rows 0,1,2 -> A,B,C; write rows 0,1 to slots 0,1.
  LOADSET(A0,A1,A2,A3,A4);
  LOADSET(B0,B1,B2,B3,B4);
  LOADSET(C0,C1,C2,C3,C4);          // gIss now at row 3
  int wslot = 0;
  float* lsWr = ringl;
  float* oSt = out0n + loff;        // fwd rows ascend from 0
  WAITVM(10);                       // cert row 0 (newer = rows 1,2)
  WRITESET(A0,A1,A2,A3,A4);         // slot 0 (+ fwd store row 0)
  if constexpr (!DIR) { WAITVM(10); } else { WAITVM(5); }  // cert row 1
  WRITESET(B0,B1,B2,B3,B4);         // slot 1 (+ fwd store row 1)
  barrier_lgkm();                   // prologue barrier (#1)

#define LSTEP(I0,I1,I2,I3,I4, W0,W1,W2,W3,W4) do { \
    LOADSET(I0,I1,I2,I3,I4); \
    if constexpr (!DIR) { WAITVM(10); } else { WAITVM(5); } \
    WRITESET(W0,W1,W2,W3,W4); \
    barrier_lgkm(); } while (0)

  // Steady: s = 0..794 (265 chunks of 3; sets rotate A,B,C statically).
  for (int c = 0; c < 265; ++c) {
    LSTEP(A0,A1,A2,A3,A4, C0,C1,C2,C3,C4);  // s%3==0: issue s+3 (A), write s+2 (C)
    LSTEP(B0,B1,B2,B3,B4, A0,A1,A2,A3,A4);  // s%3==1
    LSTEP(C0,C1,C2,C3,C4, B0,B1,B2,B3,B4);  // s%3==2
  }
  // s=795: issue row 798 (A), write row 797 (C).
  LSTEP(A0,A1,A2,A3,A4, C0,C1,C2,C3,C4);
  // s=796: issue row 799 (B), write row 798 (A).
  LSTEP(B0,B1,B2,B3,B4, A0,A1,A2,A3,A4);
  // s=797: no issue; cert row 799 (newer = fwd St(798) only), write it (B).
  if constexpr (!DIR) { WAITVM(5); } else { WAITVM(0); }
  WRITESET(B0,B1,B2,B3,B4);
  barrier_lgkm();
  // s=798, 799: barrier only.
  barrier_lgkm();
  barrier_lgkm();
#undef LSTEP
#undef WRITESET
#undef LOADSET
}

// ---------------- compute waves (waves 0..3) ----------------
// DIR=0 (fwd): thread u owns states {4u..4u+3}; gathers abuf[u>>2 + 256k].
// DIR=1 (bwd): thread u owns states {u+256j}; gathers abuf[4u..4u+3].
template <int DIR>
__device__ void compute_run(float* __restrict__ out, int n, int u,
                            const float* __restrict__ ring, float (*abuf)[SST]) {
  float* outn = out + (size_t)n * (T_STEPS + 1) * SST;
  float a[4] = {0.f, 0.f, 0.f, 0.f};

  {
    const float4 z = {0.f, 0.f, 0.f, 0.f};
    *(float4*)&abuf[0][4 * u] = z;
    const size_t t0 = DIR ? (size_t)T_STEPS : 0;
    ((float4*)(outn + t0 * SST))[u] = z;
  }
  barrier_lgkm();   // prologue barrier (#1); slots 0,1 now valid

  const float* rb = ring;   // slot 0
  int slot = 0;
  for (int s = 0; s < T_STEPS; ++s) {
    const int cur = s & 1, nxt = cur ^ 1;
    const float4* rv = (const float4*)(rb + 20 * u);
    const float4 q0 = rv[0], q1 = rv[1], q2 = rv[2], q3 = rv[3], q4 = rv[4];
    float fv[20];
    fv[0]=q0.x; fv[1]=q0.y; fv[2]=q0.z; fv[3]=q0.w;
    fv[4]=q1.x; fv[5]=q1.y; fv[6]=q1.z; fv[7]=q1.w;
    fv[8]=q2.x; fv[9]=q2.y; fv[10]=q2.z; fv[11]=q2.w;
    fv[12]=q3.x; fv[13]=q3.y; fv[14]=q3.z; fv[15]=q3.w;
    fv[16]=q4.x; fv[17]=q4.y; fv[18]=q4.z; fv[19]=q4.w;

    float na[4];
    if constexpr (!DIR) {
      const int q = u >> 2;
      const float p0 = abuf[cur][q];
      const float p1 = abuf[cur][q + 256];
      const float p2 = abuf[cur][q + 512];
      const float p3 = abuf[cur][q + 768];
#pragma unroll
      for (int j = 0; j < 4; ++j) {
        na[j] = lse5(fv[5*j] + a[j], fv[5*j+1] + p0, fv[5*j+2] + p1,
                     fv[5*j+3] + p2, fv[5*j+4] + p3);
        a[j] = na[j];
      }
      const float4 o = {na[0], na[1], na[2], na[3]};
      ((float4*)(outn + (size_t)(s + 1) * SST))[u] = o;
      *(float4*)&abuf[nxt][4 * u] = o;
    } else {
      const float4 pv = *(const float4*)&abuf[cur][4 * u];
      const float s0 = rb[5*u], s1 = rb[5*u+1280], s2 = rb[5*u+2560], s3 = rb[5*u+3840];
      const int t = T_STEPS - 1 - s;
      na[0] = lse5(s0 + a[0], fv[1] + pv.x, fv[6] + pv.y, fv[11] + pv.z, fv[16] + pv.w);
      na[1] = lse5(s1 + a[1], fv[2] + pv.x, fv[7] + pv.y, fv[12] + pv.z, fv[17] + pv.w);
      na[2] = lse5(s2 + a[2], fv[3] + pv.x, fv[8] + pv.y, fv[13] + pv.z, fv[18] + pv.w);
      na[3] = lse5(s3 + a[3], fv[4] + pv.x, fv[9] + pv.y, fv[14] + pv.z, fv[19] + pv.w);
#pragma unroll
      for (int j = 0; j < 4; ++j) {
        a[j] = na[j];
        outn[(size_t)t * SST + u + 256 * j] = na[j];
        abuf[nxt][u + 256 * j] = na[j];
      }
    }
    barrier_lgkm();
    slot = (slot + 1) & (NSLOT - 1);
    rb = ring + slot * ROW;
  }
}

__global__ __launch_bounds__(512, 1) void mega(const float* __restrict__ scores,
                                               float* __restrict__ out0,
                                               float* __restrict__ bwdo,
                                               float* __restrict__ fposts) {
  __shared__ float ring[NSLOT * ROW];   // 80 KB linear ring
  __shared__ float abuf[2][SST];        // 8 KB
  const int b = blockIdx.x;
  const int tid = threadIdx.x;
  const int n = (b < NBATCH) ? b : (b - NBATCH);
  const float* base = scores + (size_t)n * ROW;

  if (b < NBATCH) {
    if (tid < 256) compute_run<0>(fposts, n, tid, ring, abuf);
    else loader_run<0>(base, out0 + (size_t)n * T_STEPS * ROW,
                       (tid >> 6) - 4, tid & 63, ring);
  } else {
    if (tid < 256) compute_run<1>(bwdo, n, tid, ring, abuf);
    else loader_run<1>(base, nullptr, (tid >> 6) - 4, tid & 63, ring);
  }
}

// One wave per row of 1024: posts = softmax(fwd + bwd), in place over fwd buffer.
__global__ __launch_bounds__(256) void posts_kernel(float* __restrict__ fp,
                                                    const float* __restrict__ bp) {
  const int lane = threadIdx.x & 63;
  const int wid  = threadIdx.x >> 6;
  const size_t row = (size_t)blockIdx.x * 4 + wid;
  float* f = fp + row * SST;
  const float* b = bp + row * SST;

  float x[16];
#pragma unroll
  for (int k = 0; k < 4; ++k) {
    const float4 fv = ((const float4*)f)[lane + 64 * k];
    const float4 bv = ((const float4*)b)[lane + 64 * k];
    x[4 * k + 0] = fv.x + bv.x;
    x[4 * k + 1] = fv.y + bv.y;
    x[4 * k + 2] = fv.z + bv.z;
    x[4 * k + 3] = fv.w + bv.w;
  }
  float m = x[0];
#pragma unroll
  for (int j = 1; j < 16; ++j) m = fmaxf(m, x[j]);
#pragma unroll
  for (int off = 32; off >= 1; off >>= 1) m = fmaxf(m, __shfl_xor(m, off));
  float ssum = 0.0f;
#pragma unroll
  for (int j = 0; j < 16; ++j) { x[j] = __expf(x[j] - m); ssum += x[j]; }
#pragma unroll
  for (int off = 32; off >= 1; off >>= 1) ssum += __shfl_xor(ssum, off);
  const float inv = 1.0f / ssum;
#pragma unroll
  for (int k = 0; k < 4; ++k) {
    float4 o;
    o.x = x[4 * k + 0] * inv;
    o.y = x[4 * k + 1] * inv;
    o.z = x[4 * k + 2] * inv;
    o.w = x[4 * k + 3] * inv;
    ((float4*)f)[lane + 64 * k] = o;
  }
}

extern "C" void kernel_launch(void* const* d_in, const int* in_sizes, int n_in,
                              void* d_out, int out_size, void* d_ws, size_t ws_size,
                              hipStream_t stream) {
  (void)in_sizes; (void)n_in; (void)d_ws; (void)ws_size; (void)out_size;
  const float* scores = (const float*)d_in[0];
  float* out = (float*)d_out;
  float* out0   = out;                                                  // (32,800,5120)
  float* bwdo   = out + (size_t)NBATCH * T_STEPS * ROW;                 // (32,801,1024)
  float* fposts = bwdo + (size_t)NBATCH * (T_STEPS + 1) * SST;          // (32,801,1024)

  mega<<<2 * NBATCH, 512, 0, stream>>>(scores, out0, bwdo, fposts);
  posts_kernel<<<(NBATCH * (T_STEPS + 1)) / 4, 256, 0, stream>>>(fposts, bwdo);
}